// Round 14
// baseline (484.930 us; speedup 1.0000x reference)
//
#include <hip/hip_runtime.h>
#include <hip/hip_bf16.h>
#include <stdint.h>

typedef __bf16 bf16_t;
typedef bf16_t bf16x8 __attribute__((ext_vector_type(8)));
typedef bf16_t bf16x4 __attribute__((ext_vector_type(4)));
typedef float  f32x4  __attribute__((ext_vector_type(4)));

#define B_DIM 16384

#define BARM()   do { asm volatile("" ::: "memory"); \
                      __builtin_amdgcn_s_barrier();  \
                      asm volatile("" ::: "memory"); } while (0)
#define MEMF()   asm volatile("" ::: "memory")
#define LGKM0()  asm volatile("s_waitcnt lgkmcnt(0)" ::: "memory")
#define VMCNT6() asm volatile("s_waitcnt vmcnt(6)" ::: "memory")
#define VMCNT2() asm volatile("s_waitcnt vmcnt(2)" ::: "memory")
#define VMCNT0() asm volatile("s_waitcnt vmcnt(0)" ::: "memory")

// async global->LDS, 16B per lane; LDS dest is wave-uniform base (+lane*16 by HW)
__device__ __forceinline__ void async_copy16(void* lptr, const void* gptr) {
  __builtin_amdgcn_global_load_lds(
      (const __attribute__((address_space(1))) unsigned int*)gptr,
      (__attribute__((address_space(3))) unsigned int*)lptr, 16, 0, 0);
}

// ---------------- cast w1/w2 fp32 -> bf16 (x fused into GEMM1) ----------------
__global__ void cast_w_kernel(const float* __restrict__ w1, const float* __restrict__ w2,
                              bf16_t* __restrict__ w1b, bf16_t* __restrict__ w2b) {
  const float* src = blockIdx.y ? w2 : w1;
  bf16_t* dst = blockIdx.y ? w2b : w1b;
  size_t i = ((size_t)blockIdx.x * 256 + threadIdx.x) * 8;
  f32x4 a = *(const f32x4*)(src + i);
  f32x4 b = *(const f32x4*)(src + i + 4);
  bf16x8 o;
  o[0]=(bf16_t)a[0]; o[1]=(bf16_t)a[1]; o[2]=(bf16_t)a[2]; o[3]=(bf16_t)a[3];
  o[4]=(bf16_t)b[0]; o[5]=(bf16_t)b[1]; o[6]=(bf16_t)b[2]; o[7]=(bf16_t)b[3];
  *(bf16x8*)(dst + i) = o;
}

// ============ GEMM1 fused-x: 256x256, BK=64, 8 waves, 16x16x32 bf16 ===========
// A = x (fp32) reg-staged IN-PHASE (load+cvt+ds_write, zero cross-barrier reg
// liveness); B via global_load_lds. MFMA pairing M0x{N0,N1} / M1x{N0,N1} so
// only bN0,bN1 (32 VGPR) live across each barrier (frees regs for staging).
//   Q1: rd aM0,bN0,bN1(buf0) | fuse A(t0+1)->buf1 | DMA B1(t0+1) | lgkm0
//   Q2: rd aM1(buf0)         | DMA B0(t0+2)       | vmcnt(2) gate (pub t0+1)
//   Q3: rd aM0,bN0,bN1(buf1) | fuse A(t0+2)->buf0 | DMA B1(t0+2) | lgkm0
//   Q4: rd aM1(buf1)         | DMA B0(t0+3)       | vmcnt(2) gate (pub t0+2)
// Region-safety: every write targets a region whose last read issued >=1
// barrier earlier (same in-pipe-order argument the DMA stages already use).
// vmcnt ledger: each gate's preceding ACVTX auto-drain clears all loads up to
// its own A-loads; remaining = 1 B-stage [2] -> vmcnt(2) completes the tile.
__global__ __launch_bounds__(512, 2)
void monarch_gemm1f(const float* __restrict__ Xf, const bf16_t* __restrict__ Wb,
                    bf16_t* __restrict__ Outb)
{
  __shared__ __align__(16) char smem[131072];
  const int tid  = threadIdx.x;
  const int lane = tid & 63;
  const int wid  = tid >> 6;
  const int wm   = wid >> 2;
  const int wn   = wid & 3;

  const int pb = blockIdx.x;
  const int lb = (pb & 7) * 128 + (pb >> 3);
  const int zi = lb >> 8;
  const int mt = (lb & 255) >> 2;
  const int nt = lb & 3;

  const size_t brow0 = (size_t)mt * 256;
  const int    ncol0 = nt * 256;

  const float*  Axf  = Xf + brow0 * 4096 + (size_t)zi * 1024;           // fp32
  const bf16_t* Bsrc = Wb + ((size_t)zi << 20) + (size_t)ncol0 * 1024;  // bf16

  const int sRow = lane >> 3;
  const int sC   = (lane & 7) ^ sRow;

// B-only DMA stage: H=2 (B0) or 3 (B1)
#define STAGEB(BUF, T, H) do {                                                  \
    const bf16_t* _s = Bsrc + ((size_t)(((H)-2) * 128) * 1024) + (T) * 64;      \
    async_copy16(smem + (BUF)*65536 + 32768 + ((H)&1)*16384 + wid*1024,         \
                 _s + (size_t)(wid * 8 + sRow) * 1024 + sC * 8);                \
    async_copy16(smem + (BUF)*65536 + 32768 + ((H)&1)*16384 + 8192 + wid*1024,  \
                 _s + (size_t)(64 + wid * 8 + sRow) * 1024 + sC * 8);           \
  } while (0)

  // fused A staging: 4 rows/thread (ar..ar+3), 8 fp32 per row-chunk
  const int ar = (tid >> 3) * 4;
  const int ac = tid & 7;
  f32x4 aw[8];
#define ALOADX(T) do { MEMF();                                                  \
    _Pragma("unroll") for (int q = 0; q < 4; ++q) {                             \
      const float* _p = Axf + (size_t)(ar + q) * 4096 + (T) * 64 + ac * 8;      \
      aw[2*q] = *(const f32x4*)_p; aw[2*q+1] = *(const f32x4*)(_p + 4); }       \
    MEMF(); } while (0)
#define ACVTX(BUF) do { MEMF();                                                 \
    _Pragma("unroll") for (int q = 0; q < 4; ++q) {                             \
      f32x4 _u = aw[2*q], _v = aw[2*q+1]; bf16x8 _pk;                           \
      _pk[0]=(bf16_t)_u[0]; _pk[1]=(bf16_t)_u[1]; _pk[2]=(bf16_t)_u[2];         \
      _pk[3]=(bf16_t)_u[3]; _pk[4]=(bf16_t)_v[0]; _pk[5]=(bf16_t)_v[1];         \
      _pk[6]=(bf16_t)_v[2]; _pk[7]=(bf16_t)_v[3];                               \
      const int _r = ar + q;                                                    \
      *(bf16x8*)(smem + (BUF)*65536 + _r * 128 + ((ac ^ (_r & 7)) * 16)) = _pk; } \
    MEMF(); } while (0)

  const int cs0 = ((0 + (lane >> 4)) ^ (lane & 7)) * 16;
  const int cs1 = ((4 + (lane >> 4)) ^ (lane & 7)) * 16;
  const int aBase = (wm * 128 + (lane & 15)) * 128;
  const int bBase = 32768 + (wn * 64 + (lane & 15)) * 128;

#define RDA(buf, m, kk) (*(const bf16x8*)(smem + (buf)*65536 + aBase + (m)*2048 + ((kk)?cs1:cs0)))
#define RDB(buf, n, kk) (*(const bf16x8*)(smem + (buf)*65536 + bBase + (n)*2048 + ((kk)?cs1:cs0)))

  f32x4 acc[8][4] = {};
  bf16x8 aM0[4][2], aM1[4][2], bN0[2][2], bN1[2][2];

// one A-half x full N: 32 MFMA
#define MFMA_M(AR, Aarr)                                                           \
  __builtin_amdgcn_s_setprio(1);                                                   \
  _Pragma("unroll") for (int m = 0; m < 4; ++m)                                    \
  _Pragma("unroll") for (int n = 0; n < 2; ++n)                                    \
  _Pragma("unroll") for (int kk = 0; kk < 2; ++kk) {                               \
    acc[(AR)+m][n]   = __builtin_amdgcn_mfma_f32_16x16x32_bf16(                    \
        Aarr[m][kk], bN0[n][kk], acc[(AR)+m][n], 0, 0, 0);                         \
    acc[(AR)+m][2+n] = __builtin_amdgcn_mfma_f32_16x16x32_bf16(                    \
        Aarr[m][kk], bN1[n][kk], acc[(AR)+m][2+n], 0, 0, 0);                       \
  }                                                                                \
  __builtin_amdgcn_s_setprio(0);

#define LD_A0(buf) _Pragma("unroll") for (int m = 0; m < 4; ++m) { \
    aM0[m][0] = RDA(buf,m,0); aM0[m][1] = RDA(buf,m,1); }
#define LD_A1(buf) _Pragma("unroll") for (int m = 0; m < 4; ++m) { \
    aM1[m][0] = RDA(buf,m+4,0); aM1[m][1] = RDA(buf,m+4,1); }
#define LD_B0(buf) _Pragma("unroll") for (int n = 0; n < 2; ++n) { \
    bN0[n][0] = RDB(buf,n,0); bN0[n][1] = RDB(buf,n,1); }
#define LD_B1(buf) _Pragma("unroll") for (int n = 0; n < 2; ++n) { \
    bN1[n][0] = RDB(buf,n+2,0); bN1[n][1] = RDB(buf,n+2,1); }

  // ---- prologue: A(T0)->buf0 fused; B0,B1(T0) + B0(T1) DMA ----
  ALOADX(0); ACVTX(0);
  STAGEB(0,0,2); MEMF(); STAGEB(0,0,3); MEMF();
  STAGEB(1,1,2);
  VMCNT2(); LGKM0(); BARM();   // T0's B complete; B0(T1) in flight; A(T0) published

  for (int it2 = 0; it2 < 8; ++it2) {
    const int t0 = it2 * 2;
    const bool nl = (it2 < 7);
    // ---- Q1: rd aM0,bN0,bN1(buf0) ; fuse A(t0+1)->buf1 ; DMA B1(t0+1) ----
    ALOADX(t0+1);
    LD_A0(0); LD_B0(0); LD_B1(0);
    ACVTX(1);
    MEMF(); STAGEB(1, t0+1, 3);
    LGKM0();
    BARM();
    MFMA_M(0, aM0);
    // ---- Q2: rd aM1(buf0) ; DMA B0(t0+2) ; gate publish buf1(t0+1) ----
    LD_A1(0);
    if (nl) { MEMF(); STAGEB(0, t0+2, 2); VMCNT2(); }
    else    { VMCNT0(); }
    BARM();
    MFMA_M(4, aM1);
    // ---- Q3: rd aM0,bN0,bN1(buf1) ; fuse A(t0+2)->buf0 ; DMA B1(t0+2) ----
    if (nl) ALOADX(t0+2);
    LD_A0(1); LD_B0(1); LD_B1(1);
    if (nl) { ACVTX(0); MEMF(); STAGEB(0, t0+2, 3); LGKM0(); }
    BARM();
    MFMA_M(0, aM0);
    // ---- Q4: rd aM1(buf1) ; DMA B0(t0+3) ; gate publish buf0(t0+2) ----
    LD_A1(1);
    if (nl) { MEMF(); STAGEB(1, t0+3, 2); VMCNT2(); }
    BARM();
    MFMA_M(4, aM1);
  }

  // ---- epilogue: P1 scatter via [128][4][72] LDS layout (vmem drained) ----
  bf16_t* C0 = (bf16_t*)smem;
  #pragma unroll
  for (int half = 0; half < 2; ++half) {
    BARM();
    if (wm == half) {
      const int rg = lane >> 4, cl = lane & 15;
      const int l = cl & 3, rvb = cl >> 2;
      #pragma unroll
      for (int m = 0; m < 8; ++m)
        #pragma unroll
        for (int n = 0; n < 4; ++n) {
          const int rowb = (m * 16 + rg * 4) * 288 + l * 72 + wn * 16 + n * 4 + rvb;
          #pragma unroll
          for (int j = 0; j < 4; ++j)
            C0[rowb + j * 288] = (bf16_t)acc[m][n][j];
        }
    }
    BARM();
    #pragma unroll
    for (int i = 0; i < 8; ++i) {
      const int s = i * 512 + tid;
      const int row = s >> 5, l2 = (s >> 3) & 3, part = s & 7;
      bf16x8 v = *(const bf16x8*)&C0[row * 288 + l2 * 72 + part * 8];
      *(bf16x8*)&Outb[(brow0 + half * 128 + row) * 4096 +
                      l2 * 1024 + zi * 256 + nt * 64 + part * 8] = v;
    }
  }
#undef RDA
#undef RDB
#undef MFMA_M
#undef LD_A0
#undef LD_A1
#undef LD_B0
#undef LD_B1
#undef STAGEB
#undef ALOADX
#undef ACVTX
}

// ============ GEMM2: R13 fat-phase kernel, EPI1 contiguous (unchanged) ========
__global__ __launch_bounds__(512, 2)
void monarch_gemm2(const bf16_t* __restrict__ Ab, const bf16_t* __restrict__ Wb,
                   bf16_t* __restrict__ Outb)
{
  __shared__ __align__(16) char smem[131072];
  const int tid  = threadIdx.x;
  const int lane = tid & 63;
  const int wid  = tid >> 6;
  const int wm   = wid >> 2;
  const int wn   = wid & 3;

  const int pb = blockIdx.x;
  const int lb = (pb & 7) * 128 + (pb >> 3);
  const int zi = lb >> 8;
  const int mt = (lb & 255) >> 2;
  const int nt = lb & 3;

  const size_t brow0 = (size_t)mt * 256;
  const int    ncol0 = nt * 256;

  const bf16_t* Asrc = Ab + brow0 * 4096 + (size_t)zi * 1024;
  const bf16_t* Bsrc = Wb + ((size_t)zi << 20) + (size_t)ncol0 * 1024;

  const int sRow = lane >> 3;
  const int sC   = (lane & 7) ^ sRow;

#define STAGE(BUF, T, H) do {                                                   \
    const bf16_t* _s = (H) < 2 ? Asrc + ((size_t)((H) * 128) * 4096) + (T) * 64 \
                               : Bsrc + ((size_t)(((H)-2) * 128) * 1024) + (T) * 64; \
    const size_t _st = (H) < 2 ? 4096 : 1024;                                   \
    async_copy16(smem + (BUF)*65536 + ((H)>>1)*32768 + ((H)&1)*16384 + wid*1024,\
                 _s + (size_t)(wid * 8 + sRow) * _st + sC * 8);                 \
    async_copy16(smem + (BUF)*65536 + ((H)>>1)*32768 + ((H)&1)*16384 + 8192 + wid*1024, \
                 _s + (size_t)(64 + wid * 8 + sRow) * _st + sC * 8);            \
  } while (0)

  const int cs0 = ((0 + (lane >> 4)) ^ (lane & 7)) * 16;
  const int cs1 = ((4 + (lane >> 4)) ^ (lane & 7)) * 16;
  const int aBase = (wm * 128 + (lane & 15)) * 128;
  const int bBase = 32768 + (wn * 64 + (lane & 15)) * 128;

#define RDA(buf, m, kk) (*(const bf16x8*)(smem + (buf)*65536 + aBase + (m)*2048 + ((kk)?cs1:cs0)))
#define RDB(buf, n, kk) (*(const bf16x8*)(smem + (buf)*65536 + bBase + (n)*2048 + ((kk)?cs1:cs0)))

  f32x4 acc[8][4] = {};
  bf16x8 aM0[4][2], aM1[4][2], bN0[2][2], bN1[2][2];

#define MFMA_QUAD(AR, Aarr, NB, Barr)                                              \
  _Pragma("unroll") for (int m = 0; m < 4; ++m)                                    \
  _Pragma("unroll") for (int n = 0; n < 2; ++n)                                    \
  _Pragma("unroll") for (int kk = 0; kk < 2; ++kk)                                 \
    acc[(AR)+m][(NB)+n] = __builtin_amdgcn_mfma_f32_16x16x32_bf16(                 \
        Aarr[m][kk], Barr[n][kk], acc[(AR)+m][(NB)+n], 0, 0, 0);

#define LD_A0(buf) _Pragma("unroll") for (int m = 0; m < 4; ++m) { \
    aM0[m][0] = RDA(buf,m,0); aM0[m][1] = RDA(buf,m,1); }
#define LD_A1(buf) _Pragma("unroll") for (int m = 0; m < 4; ++m) { \
    aM1[m][0] = RDA(buf,m+4,0); aM1[m][1] = RDA(buf,m+4,1); }
#define LD_B0(buf) _Pragma("unroll") for (int n = 0; n < 2; ++n) { \
    bN0[n][0] = RDB(buf,n,0); bN0[n][1] = RDB(buf,n,1); }
#define LD_B1(buf) _Pragma("unroll") for (int n = 0; n < 2; ++n) { \
    bN1[n][0] = RDB(buf,n+2,0); bN1[n][1] = RDB(buf,n+2,1); }

  STAGE(0,0,0); MEMF(); STAGE(0,0,1); MEMF(); STAGE(0,0,2); MEMF(); STAGE(0,0,3); MEMF();
  STAGE(1,1,0); MEMF(); STAGE(1,1,1); MEMF(); STAGE(1,1,2);
  VMCNT6(); BARM();

  for (int it2 = 0; it2 < 8; ++it2) {
    const int t0 = it2 * 2;
    const bool nl = (it2 < 7);
    LD_A0(0); LD_B0(0); LD_A1(0);
    MEMF(); STAGE(1, t0+1, 3);
    BARM();
    __builtin_amdgcn_s_setprio(1);
    MFMA_QUAD(0, aM0, 0, bN0);
    MFMA_QUAD(4, aM1, 0, bN0);
    __builtin_amdgcn_s_setprio(0);
    LD_B1(0);
    if (nl) { MEMF(); STAGE(0, t0+2, 0); MEMF(); STAGE(0, t0+2, 1);
              MEMF(); STAGE(0, t0+2, 2); VMCNT6(); }
    else    { VMCNT0(); }
    BARM();
    __builtin_amdgcn_s_setprio(1);
    MFMA_QUAD(0, aM0, 2, bN1);
    MFMA_QUAD(4, aM1, 2, bN1);
    __builtin_amdgcn_s_setprio(0);
    LD_A0(1); LD_B0(1); LD_A1(1);
    if (nl) { MEMF(); STAGE(0, t0+2, 3); }
    BARM();
    __builtin_amdgcn_s_setprio(1);
    MFMA_QUAD(0, aM0, 0, bN0);
    MFMA_QUAD(4, aM1, 0, bN0);
    __builtin_amdgcn_s_setprio(0);
    LD_B1(1);
    if (nl) { MEMF(); STAGE(1, t0+3, 0); MEMF(); STAGE(1, t0+3, 1);
              MEMF(); STAGE(1, t0+3, 2); VMCNT6(); }
    BARM();
    __builtin_amdgcn_s_setprio(1);
    MFMA_QUAD(0, aM0, 2, bN1);
    MFMA_QUAD(4, aM1, 2, bN1);
    __builtin_amdgcn_s_setprio(0);
  }

  bf16_t* C = (bf16_t*)smem;   // [128][264]
  #pragma unroll
  for (int half = 0; half < 2; ++half) {
    BARM();
    if (wm == half) {
      const int rg = lane >> 4, cl = lane & 15;
      #pragma unroll
      for (int m = 0; m < 8; ++m)
        #pragma unroll
        for (int n = 0; n < 4; ++n) {
          const int rl = m * 16 + rg * 4;
          const int col = wn * 64 + n * 16 + cl;
          #pragma unroll
          for (int j = 0; j < 4; ++j)
            C[(rl + j) * 264 + col] = (bf16_t)acc[m][n][j];
        }
    }
    BARM();
    #pragma unroll
    for (int i = 0; i < 8; ++i) {
      const int s = i * 512 + tid;
      const int row = s >> 5, ch = s & 31;
      bf16x8 v = *(const bf16x8*)&C[row * 264 + ch * 8];
      *(bf16x8*)&Outb[(brow0 + half * 128 + row) * 4096 +
                      (size_t)zi * 1024 + ncol0 + ch * 8] = v;
    }
  }
#undef RDA
#undef RDB
#undef MFMA_QUAD
#undef LD_A0
#undef LD_A1
#undef LD_B0
#undef LD_B1
#undef STAGE
}

// -------- P2 + bias: out[b, s*4+l] = o2[b,l,s] + bias  (16B-load version) ----
__global__ void permute_bias_kernel(const bf16_t* __restrict__ o2,
                                    const float* __restrict__ bias,
                                    float* __restrict__ out) {
  const int t = blockIdx.x * 256 + threadIdx.x;
  const int b = t >> 7;
  const int s0 = (t & 127) * 8;
  const size_t rowb = (size_t)b * 4096;
  bf16x8 vl[4];
  #pragma unroll
  for (int l = 0; l < 4; ++l) vl[l] = *(const bf16x8*)(o2 + rowb + l * 1024 + s0);
  #pragma unroll
  for (int si = 0; si < 8; ++si) {
    f32x4 bb = *(const f32x4*)(bias + (size_t)(s0 + si) * 4);
    f32x4 o;
    o[0] = (float)vl[0][si] + bb[0];
    o[1] = (float)vl[1][si] + bb[1];
    o[2] = (float)vl[2][si] + bb[2];
    o[3] = (float)vl[3][si] + bb[3];
    *(f32x4*)(out + rowb + (size_t)(s0 + si) * 4) = o;
  }
}

extern "C" void kernel_launch(void* const* d_in, const int* in_sizes, int n_in,
                              void* d_out, int out_size, void* d_ws, size_t ws_size,
                              hipStream_t stream) {
  const float* x    = (const float*)d_in[0];
  const float* w1   = (const float*)d_in[1];
  const float* w2   = (const float*)d_in[2];
  const float* bias = (const float*)d_in[3];
  float* out = (float*)d_out;

  char* ws = (char*)d_ws;
  const size_t wBytes     = (size_t)8 << 20;            // per w array (bf16)
  const size_t interBytes = (size_t)B_DIM * 4096 * 2;   // 134 MB
  bf16_t* w1b   = (bf16_t*)(ws);
  bf16_t* w2b   = (bf16_t*)(ws + wBytes);
  bf16_t* inter = (bf16_t*)(ws + 2 * wBytes);
  bf16_t* o2    = (bf16_t*)(ws + 2 * wBytes + interBytes);

  cast_w_kernel<<<dim3(2048, 2), 256, 0, stream>>>(w1, w2, w1b, w2b);
  monarch_gemm1f<<<1024, 512, 0, stream>>>(x, w1b, inter);
  monarch_gemm2<<<1024, 512, 0, stream>>>(inter, w2b, o2);
  permute_bias_kernel<<<8192, 256, 0, stream>>>(o2, bias, out);
}

// Round 15
// 460.301 us; speedup vs baseline: 1.0535x; 1.0535x over previous
//
#include <hip/hip_runtime.h>
#include <hip/hip_bf16.h>
#include <stdint.h>

typedef __bf16 bf16_t;
typedef bf16_t bf16x8 __attribute__((ext_vector_type(8)));
typedef bf16_t bf16x4 __attribute__((ext_vector_type(4)));
typedef float  f32x4  __attribute__((ext_vector_type(4)));

#define B_DIM 16384

// fenced barrier: reads/stages may not cross (they must issue pre-barrier)
#define BARM()   do { asm volatile("" ::: "memory"); \
                      __builtin_amdgcn_s_barrier();  \
                      asm volatile("" ::: "memory"); } while (0)
#define MEMF()   asm volatile("" ::: "memory")
#define VMCNT6() asm volatile("s_waitcnt vmcnt(6)" ::: "memory")
#define VMCNT0() asm volatile("s_waitcnt vmcnt(0)" ::: "memory")

// async global->LDS, 16B per lane; LDS dest is wave-uniform base (+lane*16 by HW)
__device__ __forceinline__ void async_copy16(void* lptr, const void* gptr) {
  __builtin_amdgcn_global_load_lds(
      (const __attribute__((address_space(1))) unsigned int*)gptr,
      (__attribute__((address_space(3))) unsigned int*)lptr, 16, 0, 0);
}

// ---------------- cast x + w1 + w2 fp32 -> bf16 ----------------
__global__ void cast_all_kernel(const float* __restrict__ x, const float* __restrict__ w1,
                                const float* __restrict__ w2, bf16_t* __restrict__ xb,
                                bf16_t* __restrict__ w1b, bf16_t* __restrict__ w2b) {
  size_t c = (size_t)blockIdx.x * 256 + threadIdx.x;  // 8-elem chunk id
  const float* s; bf16_t* d; size_t off;
  if (c < 8388608)      { s = x;  d = xb;  off = c; }            // 16384*4096/8
  else if (c < 8912896) { s = w1; d = w1b; off = c - 8388608; }  // 4*1024*1024/8
  else                  { s = w2; d = w2b; off = c - 8912896; }
  size_t i = off * 8;
  f32x4 a = *(const f32x4*)(s + i);
  f32x4 b = *(const f32x4*)(s + i + 4);
  bf16x8 o;
  o[0]=(bf16_t)a[0]; o[1]=(bf16_t)a[1]; o[2]=(bf16_t)a[2]; o[3]=(bf16_t)a[3];
  o[4]=(bf16_t)b[0]; o[5]=(bf16_t)b[1]; o[6]=(bf16_t)b[2]; o[7]=(bf16_t)b[3];
  *(bf16x8*)(d + i) = o;
}

// ============ 256x256 GEMM (BK=64, 8 waves, 16x16x32 bf16) ============
// 4 FAT PHASES per 2-K-tile iter (quad pairs share a B-frag); single barrier
// per phase: [reads(P); stage; (vmcnt gate); BAR; 32 MFMA].  (R12/R13 best)
//   Q1: rd aM0,bN0,aM1(buf0) | stage B1(t0+1)
//   Q2: rd bN1(buf0)         | stage A0,A1,B0(t0+2) | VM6 (publishes t0+1)
//   Q3: rd aM0,bN0,aM1(buf1) | stage B1(t0+2)
//   Q4: rd bN1(buf1)         | stage A0,A1,B0(t0+3) | VM6 (publishes t0+2)
// EPI 0: P1-scatter -> inter[b*4096 + l*1024 + r]      (GEMM1)
// EPI 1: contiguous -> o2[b*4096 + zi*1024 + s]        (GEMM2)
template<int EPI>
__global__ __launch_bounds__(512, 2)
void monarch_gemm8(const bf16_t* __restrict__ Ab, const bf16_t* __restrict__ Wb,
                   bf16_t* __restrict__ Outb)
{
  __shared__ __align__(16) char smem[131072];
  const int tid  = threadIdx.x;
  const int lane = tid & 63;
  const int wid  = tid >> 6;
  const int wm   = wid >> 2;       // 2 (M) x 4 (N) wave grid; wave tile 128x64
  const int wn   = wid & 3;

  // XCD-chunked swizzle: 1024 blocks, 128 consecutive logicals per XCD
  const int pb = blockIdx.x;
  const int lb = (pb & 7) * 128 + (pb >> 3);
  const int zi = lb >> 8;                  // k (GEMM1) or l (GEMM2)
  const int mt = (lb & 255) >> 2;          // 64 M-tiles
  const int nt = lb & 3;                   // 4 N-tiles

  const size_t brow0 = (size_t)mt * 256;
  const int    ncol0 = nt * 256;

  const bf16_t* Asrc = Ab + brow0 * 4096 + (size_t)zi * 1024;          // stride 4096
  const bf16_t* Bsrc = Wb + ((size_t)zi << 20) + (size_t)ncol0 * 1024; // stride 1024

  // staging source swizzle (T2): linear LDS chunk c' holds source chunk c'^(row&7)
  const int sRow = lane >> 3;
  const int sC   = (lane & 7) ^ sRow;

// stage half H (0=A0,1=A1,2=B0,3=B1) of K-tile T into buffer BUF (literals!)
#define STAGE(BUF, T, H) do {                                                   \
    const bf16_t* _s = (H) < 2 ? Asrc + ((size_t)((H) * 128) * 4096) + (T) * 64 \
                               : Bsrc + ((size_t)(((H)-2) * 128) * 1024) + (T) * 64; \
    const size_t _st = (H) < 2 ? 4096 : 1024;                                   \
    async_copy16(smem + (BUF)*65536 + ((H)>>1)*32768 + ((H)&1)*16384 + wid*1024,\
                 _s + (size_t)(wid * 8 + sRow) * _st + sC * 8);                 \
    async_copy16(smem + (BUF)*65536 + ((H)>>1)*32768 + ((H)&1)*16384 + 8192 + wid*1024, \
                 _s + (size_t)(64 + wid * 8 + sRow) * _st + sC * 8);            \
  } while (0)

  // ds_read addressing (swizzled): chunk c0 read at linear c0^(lane&7)
  const int cs0 = ((0 + (lane >> 4)) ^ (lane & 7)) * 16;   // kk=0
  const int cs1 = ((4 + (lane >> 4)) ^ (lane & 7)) * 16;   // kk=1
  const int aBase = (wm * 128 + (lane & 15)) * 128;
  const int bBase = 32768 + (wn * 64 + (lane & 15)) * 128;

#define RDA(buf, m, kk) (*(const bf16x8*)(smem + (buf)*65536 + aBase + (m)*2048 + ((kk)?cs1:cs0)))
#define RDB(buf, n, kk) (*(const bf16x8*)(smem + (buf)*65536 + bBase + (n)*2048 + ((kk)?cs1:cs0)))

  f32x4 acc[8][4] = {};
  bf16x8 aM0[4][2], aM1[4][2], bN0[2][2], bN1[2][2];

#define MFMA_QUAD(AR, Aarr, NB, Barr)                                              \
  _Pragma("unroll") for (int m = 0; m < 4; ++m)                                    \
  _Pragma("unroll") for (int n = 0; n < 2; ++n)                                    \
  _Pragma("unroll") for (int kk = 0; kk < 2; ++kk)                                 \
    acc[(AR)+m][(NB)+n] = __builtin_amdgcn_mfma_f32_16x16x32_bf16(                 \
        Aarr[m][kk], Barr[n][kk], acc[(AR)+m][(NB)+n], 0, 0, 0);

#define LD_A0(buf) _Pragma("unroll") for (int m = 0; m < 4; ++m) { \
    aM0[m][0] = RDA(buf,m,0); aM0[m][1] = RDA(buf,m,1); }
#define LD_A1(buf) _Pragma("unroll") for (int m = 0; m < 4; ++m) { \
    aM1[m][0] = RDA(buf,m+4,0); aM1[m][1] = RDA(buf,m+4,1); }
#define LD_B0(buf) _Pragma("unroll") for (int n = 0; n < 2; ++n) { \
    bN0[n][0] = RDB(buf,n,0); bN0[n][1] = RDB(buf,n,1); }
#define LD_B1(buf) _Pragma("unroll") for (int n = 0; n < 2; ++n) { \
    bN1[n][0] = RDB(buf,n+2,0); bN1[n][1] = RDB(buf,n+2,1); }

  // ---- prologue: T0 (4 halves, buf0) + T1 (A0,A1,B0, buf1); strict order ----
  STAGE(0,0,0); MEMF(); STAGE(0,0,1); MEMF(); STAGE(0,0,2); MEMF(); STAGE(0,0,3); MEMF();
  STAGE(1,1,0); MEMF(); STAGE(1,1,1); MEMF(); STAGE(1,1,2);
  VMCNT6(); BARM();    // T0's 8 loads landed -> buf0 ready; 6 in flight

  for (int it2 = 0; it2 < 8; ++it2) {
    const int t0 = it2 * 2;
    const bool nl = (it2 < 7);
    // ---- Q1: rd aM0,bN0,aM1(buf0) ; MFMA {M0,M1}xN0 ----
    LD_A0(0); LD_B0(0); LD_A1(0);
    MEMF(); STAGE(1, t0+1, 3);
    BARM();
    __builtin_amdgcn_s_setprio(1);
    MFMA_QUAD(0, aM0, 0, bN0);
    MFMA_QUAD(4, aM1, 0, bN0);
    __builtin_amdgcn_s_setprio(0);
    // ---- Q2: rd bN1(buf0) ; stages + publish t0+1 ; MFMA {M0,M1}xN1 ----
    LD_B1(0);
    if (nl) { MEMF(); STAGE(0, t0+2, 0); MEMF(); STAGE(0, t0+2, 1);
              MEMF(); STAGE(0, t0+2, 2); VMCNT6(); }
    else    { VMCNT0(); }
    BARM();
    __builtin_amdgcn_s_setprio(1);
    MFMA_QUAD(0, aM0, 2, bN1);
    MFMA_QUAD(4, aM1, 2, bN1);
    __builtin_amdgcn_s_setprio(0);
    // ---- Q3: rd aM0,bN0,aM1(buf1) ; MFMA {M0,M1}xN0 ----
    LD_A0(1); LD_B0(1); LD_A1(1);
    if (nl) { MEMF(); STAGE(0, t0+2, 3); }
    BARM();
    __builtin_amdgcn_s_setprio(1);
    MFMA_QUAD(0, aM0, 0, bN0);
    MFMA_QUAD(4, aM1, 0, bN0);
    __builtin_amdgcn_s_setprio(0);
    // ---- Q4: rd bN1(buf1) ; stages + publish t0+2 ; MFMA {M0,M1}xN1 ----
    LD_B1(1);
    if (nl) { MEMF(); STAGE(1, t0+3, 0); MEMF(); STAGE(1, t0+3, 1);
              MEMF(); STAGE(1, t0+3, 2); VMCNT6(); }
    BARM();
    __builtin_amdgcn_s_setprio(1);
    MFMA_QUAD(0, aM0, 2, bN1);
    MFMA_QUAD(4, aM1, 2, bN1);
    __builtin_amdgcn_s_setprio(0);
  }

  // ---- epilogue: two 128-row halves through LDS (vmcnt drained at it7 Q2) ----
  if (EPI == 0) {
    // layout [128][4][72]: row*288 + l*72 + rv
    bf16_t* C0 = (bf16_t*)smem;
    #pragma unroll
    for (int half = 0; half < 2; ++half) {
      BARM();
      if (wm == half) {
        const int rg = lane >> 4, cl = lane & 15;
        const int l = cl & 3, rvb = cl >> 2;
        #pragma unroll
        for (int m = 0; m < 8; ++m)
          #pragma unroll
          for (int n = 0; n < 4; ++n) {
            const int rowb = (m * 16 + rg * 4) * 288 + l * 72 + wn * 16 + n * 4 + rvb;
            #pragma unroll
            for (int j = 0; j < 4; ++j)
              C0[rowb + j * 288] = (bf16_t)acc[m][n][j];
          }
      }
      BARM();
      #pragma unroll
      for (int i = 0; i < 8; ++i) {
        const int s = i * 512 + tid;            // 4096 16B segments
        const int row = s >> 5, l2 = (s >> 3) & 3, part = s & 7;
        bf16x8 v = *(const bf16x8*)&C0[row * 288 + l2 * 72 + part * 8];
        *(bf16x8*)&Outb[(brow0 + half * 128 + row) * 4096 +
                        l2 * 1024 + zi * 256 + nt * 64 + part * 8] = v;
      }
    }
  } else {
    bf16_t* C = (bf16_t*)smem;   // [128][264] padded
    #pragma unroll
    for (int half = 0; half < 2; ++half) {
      BARM();
      if (wm == half) {
        const int rg = lane >> 4, cl = lane & 15;
        #pragma unroll
        for (int m = 0; m < 8; ++m)
          #pragma unroll
          for (int n = 0; n < 4; ++n) {
            const int rl = m * 16 + rg * 4;
            const int col = wn * 64 + n * 16 + cl;
            #pragma unroll
            for (int j = 0; j < 4; ++j)
              C[(rl + j) * 264 + col] = (bf16_t)acc[m][n][j];
          }
      }
      BARM();
      #pragma unroll
      for (int i = 0; i < 8; ++i) {
        const int s = i * 512 + tid;
        const int row = s >> 5, ch = s & 31;
        bf16x8 v = *(const bf16x8*)&C[row * 264 + ch * 8];
        *(bf16x8*)&Outb[(brow0 + half * 128 + row) * 4096 +
                        (size_t)zi * 1024 + ncol0 + ch * 8] = v;
      }
    }
  }
#undef RDA
#undef RDB
#undef MFMA_QUAD
#undef LD_A0
#undef LD_A1
#undef LD_B0
#undef LD_B1
#undef STAGE
}

// -------- P2 + bias: out[b, s*4+l] = o2[b,l,s] + bias  (16B-load version) ----
// thread handles s0..s0+7 for one b-row: 4x bf16x8 loads (16B), 8x f32x4 stores
__global__ void permute_bias_kernel(const bf16_t* __restrict__ o2,
                                    const float* __restrict__ bias,
                                    float* __restrict__ out) {
  const int t = blockIdx.x * 256 + threadIdx.x;
  const int b = t >> 7;
  const int s0 = (t & 127) * 8;
  const size_t rowb = (size_t)b * 4096;
  bf16x8 vl[4];
  #pragma unroll
  for (int l = 0; l < 4; ++l) vl[l] = *(const bf16x8*)(o2 + rowb + l * 1024 + s0);
  #pragma unroll
  for (int si = 0; si < 8; ++si) {
    f32x4 bb = *(const f32x4*)(bias + (size_t)(s0 + si) * 4);
    f32x4 o;
    o[0] = (float)vl[0][si] + bb[0];
    o[1] = (float)vl[1][si] + bb[1];
    o[2] = (float)vl[2][si] + bb[2];
    o[3] = (float)vl[3][si] + bb[3];
    *(f32x4*)(out + rowb + (size_t)(s0 + si) * 4) = o;
  }
}

extern "C" void kernel_launch(void* const* d_in, const int* in_sizes, int n_in,
                              void* d_out, int out_size, void* d_ws, size_t ws_size,
                              hipStream_t stream) {
  const float* x    = (const float*)d_in[0];
  const float* w1   = (const float*)d_in[1];
  const float* w2   = (const float*)d_in[2];
  const float* bias = (const float*)d_in[3];
  float* out = (float*)d_out;

  char* ws = (char*)d_ws;
  const size_t xbBytes    = (size_t)B_DIM * 4096 * 2;   // 134 MB
  const size_t wBytes     = (size_t)8 << 20;            // per w array (bf16)
  bf16_t* xb    = (bf16_t*)(ws);
  bf16_t* w1b   = (bf16_t*)(ws + xbBytes);
  bf16_t* w2b   = (bf16_t*)(ws + xbBytes + wBytes);
  bf16_t* inter = (bf16_t*)(ws + xbBytes + 2 * wBytes);
  bf16_t* o2    = xb;   // xb dead after GEMM1; reuse for o2

  cast_all_kernel<<<36864, 256, 0, stream>>>(x, w1, w2, xb, w1b, w2b);
  monarch_gemm8<0><<<1024, 512, 0, stream>>>(xb, w1b, inter);
  monarch_gemm8<1><<<1024, 512, 0, stream>>>(inter, w2b, o2);
  permute_bias_kernel<<<8192, 256, 0, stream>>>(o2, bias, out);
}